// Round 1
// baseline (220.567 us; speedup 1.0000x reference)
//
#include <hip/hip_runtime.h>

// DynamicDilationUnfold: B=4, C=64, H=W=128, G=4, Cg=16, K=3, stride=1, pad=1.
// Ho=Wo=128. out[b][((g*Cg+cg)*K+kh)*K+kw][ho*Wo+wo], fp32.
// One thread per (b,g,ho,wo): weights/indices shared across the 16 group
// channels; stores coalesced over wo.

constexpr int B  = 4;
constexpr int C  = 64;
constexpr int H  = 128;
constexpr int W  = 128;
constexpr int G  = 4;
constexpr int Cg = C / G;           // 16
constexpr int K  = 3;
constexpr int Ho = 128;
constexpr int Wo = 128;
constexpr int HW = H * W;           // 16384
constexpr int HoWo = Ho * Wo;       // 16384

__global__ __launch_bounds__(256) void ddu_kernel(
    const float* __restrict__ x,      // (B, C, H, W)
    const float* __restrict__ dmap,   // (B, G, H, W)
    float* __restrict__ out)          // (B, C*K*K, Ho*Wo)
{
    const int idx = blockIdx.x * 256 + threadIdx.x;   // over B*G*Ho*Wo
    const int wo = idx & (Wo - 1);
    const int ho = (idx >> 7) & (Ho - 1);
    const int g  = (idx >> 14) & (G - 1);
    const int b  = idx >> 16;

    const float d = dmap[idx];        // dmap layout == (B,G,Ho,Wo) == idx order

    const float* __restrict__ xg = x + (size_t)(b * C + g * Cg) * HW;
    float* __restrict__ outg = out
        + (size_t)((b * G + g) * Cg) * (K * K * HoWo)
        + (size_t)(ho * Wo + wo);

#pragma unroll
    for (int kh = 0; kh < K; ++kh) {
        const float ph  = (float)(ho - 1) + (float)kh * d;
        const float h0f = floorf(ph);
        const float lh  = ph - h0f;
        const int h0 = (int)h0f;
        const int h1 = h0 + 1;
        const bool h0v = (unsigned)h0 < (unsigned)H;
        const bool h1v = (unsigned)h1 < (unsigned)H;
        const int h0c = min(max(h0, 0), H - 1);
        const int h1c = min(max(h1, 0), H - 1);

#pragma unroll
        for (int kw = 0; kw < K; ++kw) {
            const float pw  = (float)(wo - 1) + (float)kw * d;
            const float w0f = floorf(pw);
            const float lw  = pw - w0f;
            const int w0 = (int)w0f;
            const int w1 = w0 + 1;
            const bool w0v = (unsigned)w0 < (unsigned)W;
            const bool w1v = (unsigned)w1 < (unsigned)W;
            const int w0c = min(max(w0, 0), W - 1);
            const int w1c = min(max(w1, 0), W - 1);

            const float c00 = (1.f - lh) * (1.f - lw) * (float)(h0v && w0v);
            const float c01 = (1.f - lh) * lw          * (float)(h0v && w1v);
            const float c10 = lh          * (1.f - lw) * (float)(h1v && w0v);
            const float c11 = lh          * lw          * (float)(h1v && w1v);

            const int i00 = h0c * W + w0c;
            const int i01 = h0c * W + w1c;
            const int i10 = h1c * W + w0c;
            const int i11 = h1c * W + w1c;

            float* __restrict__ o = outg + (size_t)(kh * K + kw) * HoWo;
            const float* __restrict__ xc = xg;

#pragma unroll 4
            for (int cg = 0; cg < Cg; ++cg) {
                const float v = c00 * xc[i00] + c01 * xc[i01]
                              + c10 * xc[i10] + c11 * xc[i11];
                o[(size_t)cg * (K * K * HoWo)] = v;
                xc += HW;
            }
        }
    }
}

extern "C" void kernel_launch(void* const* d_in, const int* in_sizes, int n_in,
                              void* d_out, int out_size, void* d_ws, size_t ws_size,
                              hipStream_t stream) {
    const float* x    = (const float*)d_in[0];
    const float* dmap = (const float*)d_in[1];
    float* out = (float*)d_out;

    const int total = B * G * Ho * Wo;            // 262144 threads
    const int block = 256;
    const int grid  = total / block;              // 1024 blocks
    ddu_kernel<<<grid, block, 0, stream>>>(x, dmap, out);
}